// Round 13
// baseline (154.007 us; speedup 1.0000x reference)
//
#include <hip/hip_runtime.h>
#include <hip/hip_bf16.h>

#define HW 65536
#define WD 256
#define HD 256

typedef unsigned short u16;
typedef __attribute__((ext_vector_type(8))) short short8;
typedef __attribute__((ext_vector_type(4))) float f32x4;

__device__ __forceinline__ float frelu(float v){ return v > 0.f ? v : 0.f; }
__device__ __forceinline__ float b2f(u16 u){ unsigned v = (unsigned)u << 16; float f; __builtin_memcpy(&f, &v, 4); return f; }
__device__ __forceinline__ u16 f2b(float f){ __hip_bfloat16 h = __float2bfloat16(f); u16 u; __builtin_memcpy(&u, &h, 2); return u; }
__device__ __forceinline__ ushort4 pack4(float a, float b, float c, float d){
    ushort4 r; r.x = f2b(a); r.y = f2b(b); r.z = f2b(c); r.w = f2b(d); return r;
}

// CAT layout: LINEAR [224][HW] bf16 per image. folded channel blocks (x32 ch):
// 0=up 1=right 2=down 3=left 4=diagDR(zuoxia+zuoshang) 5=diagDL 6=diagUR
// ---------------- weight prep ----------------
__global__ void prep_weights(const float* __restrict__ w1,
                             const float* __restrict__ w2,
                             const float* __restrict__ w3,
                             float* __restrict__ wt1,   // [64][32] fp32
                             u16* __restrict__ wp2,     // [7][2][64][8] bf16 A-frags
                             u16* __restrict__ wp3) {
    int t = threadIdx.x;
    for (int idx = t; idx < 64 * 32; idx += 256) {
        int i = idx >> 5, o = idx & 31;
        wt1[idx] = w1[o * 64 + i];
    }
    // A-frag pack: lane l holds W[row=l&15 (+16*m)][k=s*32+(l>>4)*8+j]
    for (int idx = t; idx < 7 * 2 * 64 * 8; idx += 256) {
        int j = idx & 7, l = (idx >> 3) & 63, m = (idx >> 9) & 1, s = idx >> 10;
        int o = m * 16 + (l & 15);
        int k = s * 32 + ((l >> 4) * 8) + j;   // folded channel in [0,224)
        int blk = k >> 5, i = k & 31, base = o * 256;
        float v2, v3;
        if (blk < 4)        { v2 = w2[base + blk*32 + i];                   v3 = w3[base + blk*32 + i]; }
        else if (blk == 4)  { v2 = w2[base + 128 + i] + w2[base + 192 + i]; v3 = w3[base + 128 + i] + w3[base + 192 + i]; }
        else if (blk == 5)  { v2 = w2[base + 160 + i];                      v3 = w3[base + 160 + i]; }
        else                { v2 = w2[base + 224 + i];                      v3 = w3[base + 224 + i]; }
        wp2[idx] = f2b(v2);
        wp3[idx] = f2b(v3);
    }
}

// ---------------- conv1: 64ch fp32 -> 32ch bf16, vector FMA ----------------
__global__ __launch_bounds__(256) void conv1_k(const float* __restrict__ in,   // [kk][64][HW]
                                               const float* __restrict__ wt,   // [64][32]
                                               const float* __restrict__ bias,
                                               u16* __restrict__ out) {        // [kk][32][HW]
    int p = blockIdx.x * 256 + threadIdx.x;
    int b = blockIdx.y;
    const float* ip = in + (size_t)b * 64 * HW + p;
    float acc[32];
#pragma unroll
    for (int o = 0; o < 32; ++o) acc[o] = bias[o];
    constexpr int PF = 16;
    float rbuf[PF];
#pragma unroll
    for (int j = 0; j < PF; ++j) rbuf[j] = ip[(size_t)j * HW];
#pragma unroll 1
    for (int i0 = 0; i0 < 64 - PF; i0 += PF) {
        const float* ipn = ip + (size_t)(i0 + PF) * HW;
        const float* wr0 = wt + i0 * 32;
#pragma unroll
        for (int j = 0; j < PF; ++j) {
            float v = rbuf[j];
            rbuf[j] = ipn[(size_t)j * HW];
#pragma unroll
            for (int o = 0; o < 32; ++o) acc[o] = fmaf(wr0[j * 32 + o], v, acc[o]);
        }
    }
    const float* wrL = wt + (64 - PF) * 32;
#pragma unroll
    for (int j = 0; j < PF; ++j) {
        float v = rbuf[j];
#pragma unroll
        for (int o = 0; o < 32; ++o) acc[o] = fmaf(wrL[j * 32 + o], v, acc[o]);
    }
    u16* op = out + (size_t)b * 32 * HW + p;
#pragma unroll
    for (int o = 0; o < 32; ++o) op[(size_t)o * HW] = f2b(acc[o]);
}

// ---------------- row scan, one direction per wave ----------------
// DIR: 0=down 1=diagDR 2=diagDL 3=up 4=diagUR
template<int DIR>
__device__ __forceinline__ void row_scan_dir(const ushort4* __restrict__ xr,
                                             ushort4* __restrict__ ob,
                                             float wgt, int t) {
    constexpr bool FWD = (DIR <= 2);
    constexpr int D = 8;
    ushort4 buf[D];
    const int h0 = FWD ? 0 : HD - 1;
    ushort4 xu = xr[h0 * 64 + t];
    ob[h0 * 64 + t] = xu;
    float s0 = b2f(xu.x), s1 = b2f(xu.y), s2 = b2f(xu.z), s3 = b2f(xu.w);
#pragma unroll
    for (int j = 0; j < D; ++j) {
        int i = 1 + j;
        buf[j] = xr[(FWD ? i : HD - 1 - i) * 64 + t];
    }
    for (int hb = 1; hb < HD; hb += D) {
#pragma unroll
        for (int j = 0; j < D; ++j) {
            int i = hb + j;
            if (i < HD) {
                ushort4 xv = buf[j];
                int in_ = i + D; if (in_ > HD - 1) in_ = HD - 1;
                int h  = FWD ? i : HD - 1 - i;
                int hn = FWD ? in_ : HD - 1 - in_;
                buf[j] = xr[hn * 64 + t];
                float v0 = b2f(xv.x), v1 = b2f(xv.y), v2 = b2f(xv.z), v3 = b2f(xv.w);
                if (DIR == 0 || DIR == 3) {          // axial
                    s0 = frelu(fmaf(s0, wgt, v0));
                    s1 = frelu(fmaf(s1, wgt, v1));
                    s2 = frelu(fmaf(s2, wgt, v2));
                    s3 = frelu(fmaf(s3, wgt, v3));
                } else if (DIR == 1 || DIR == 4) {   // from left neighbor
                    float nb = __shfl_up(s3, 1);
                    float a0 = (t == 0) ? v0 : frelu(fmaf(nb, wgt, v0));
                    float a1 = frelu(fmaf(s0, wgt, v1));
                    float a2 = frelu(fmaf(s1, wgt, v2));
                    float a3 = frelu(fmaf(s2, wgt, v3));
                    s0 = a0; s1 = a1; s2 = a2; s3 = a3;
                } else {                             // DIR==2, from right neighbor
                    float nb = __shfl_down(s0, 1);
                    float a0 = frelu(fmaf(s1, wgt, v0));
                    float a1 = frelu(fmaf(s2, wgt, v1));
                    float a2 = frelu(fmaf(s3, wgt, v2));
                    float a3 = (t == 63) ? v3 : frelu(fmaf(nb, wgt, v3));
                    s0 = a0; s1 = a1; s2 = a2; s3 = a3;
                }
                ob[h * 64 + t] = pack4(s0, s1, s2, s3);
            }
        }
    }
}

// ---------------- merged scans: F bf16 -> CAT bf16 (linear) ----------------
// grid (104, kk), 256 thr. XCD-AFFINE mapping: all readers of channel c get
// bx%8 == c>>2 (blocks map to XCDs round-robin %8), so F channel c is
// HBM-fetched once and L2-served to its other 6 reader waves.
//  rows: bx in [0,40): d = bx>>3 (0..4), g = bx&7; wave w -> c = g*4 + w
//  cols: bx-40 = 8*(dir*4 + (c&3)) + g, g = c>>2
__global__ __launch_bounds__(256) void scan_all(const u16* __restrict__ F,    // [kk][32][HW]
                                                u16* __restrict__ CAT,        // [kk][224][HW]
                                                const float* __restrict__ irw) {
    int b = blockIdx.y;
    int bx = blockIdx.x;
    __shared__ float stile[256 * 33];
    const float wd = irw[2];
    u16* catt = CAT + (size_t)b * 224 * HW;

    if (bx < 40) {
        int d = bx >> 3;                   // direction 0..4: 0=down 1=diagDR 2=diagDL 3=up 4=diagUR
        int g = bx & 7;                    // channel group == XCD
        int wave = threadIdx.x >> 6;
        int t = threadIdx.x & 63;
        int c = g * 4 + wave;
        const ushort4* xr = (const ushort4*)(F + ((size_t)b * 32 + c) * HW);
        // CAT block per d: down->2, diagDR->4, diagDL->5, up->0, diagUR->6
        const int blkmap[5] = {2, 4, 5, 0, 6};
        ushort4* ob = (ushort4*)(catt + (size_t)(blkmap[d] * 32 + c) * HW);
        float wgt = (d == 3) ? irw[0] : wd;   // only 'up' uses wu; diagonals use wd (source bug)
        switch (d) {
            case 0: row_scan_dir<0>(xr, ob, wgt, t); break;
            case 1: row_scan_dir<1>(xr, ob, wgt, t); break;
            case 2: row_scan_dir<2>(xr, ob, wgt, t); break;
            case 3: row_scan_dir<3>(xr, ob, wgt, t); break;
            default: row_scan_dir<4>(xr, ob, wgt, t); break;
        }
    } else {
        // col scans: right(1)/left(3), LDS-tiled, double-buffered, ushort4 I/O
        int k = bx - 40;                   // 0..63
        int g = k & 7;
        int q = k >> 3;                    // 0..7 = dir*4 + (c&3)
        int dir = q >> 2;
        int c = g * 4 + (q & 3);
        int t = threadIdx.x;
        const float wgt = (dir == 0) ? irw[1] : irw[3];
        const u16* x = F + ((size_t)b * 32 + c) * HW;
        u16* o = catt + (size_t)((dir == 0 ? 1 : 3) * 32 + c) * HW;
        // I/O mapping: vec v = k*256+t -> row = v>>3, colgroup = v&7 (4 cols each)
        float r32[2][8][4];  // staged loads (converted), fully static indexing
        float carry = 0.f;
        {
            int wb0 = (dir == 0) ? 0 : 7 * 32;
#pragma unroll
            for (int kk2 = 0; kk2 < 8; ++kk2) {
                int v = kk2 * 256 + t, row = v >> 3, cg = v & 7;
                ushort4 u = *(const ushort4*)(x + row * WD + wb0 + cg * 4);
                r32[0][kk2][0] = b2f(u.x); r32[0][kk2][1] = b2f(u.y);
                r32[0][kk2][2] = b2f(u.z); r32[0][kk2][3] = b2f(u.w);
            }
        }
#pragma unroll
        for (int tw = 0; tw < 8; ++tw) {
            int wbase = (dir == 0) ? tw * 32 : (7 - tw) * 32;
            const int cur = tw & 1, nxt = cur ^ 1;
            __syncthreads();
#pragma unroll
            for (int kk2 = 0; kk2 < 8; ++kk2) {
                int v = kk2 * 256 + t, row = v >> 3, cg = v & 7;
#pragma unroll
                for (int qq = 0; qq < 4; ++qq)
                    stile[row * 33 + cg * 4 + qq] = r32[cur][kk2][qq];
            }
            __syncthreads();
            if (tw < 7) {
                int wb2 = (dir == 0) ? (tw + 1) * 32 : (6 - tw) * 32;
#pragma unroll
                for (int kk2 = 0; kk2 < 8; ++kk2) {
                    int v = kk2 * 256 + t, row = v >> 3, cg = v & 7;
                    ushort4 u = *(const ushort4*)(x + row * WD + wb2 + cg * 4);
                    r32[nxt][kk2][0] = b2f(u.x); r32[nxt][kk2][1] = b2f(u.y);
                    r32[nxt][kk2][2] = b2f(u.z); r32[nxt][kk2][3] = b2f(u.w);
                }
            }
            if (dir == 0) {
#pragma unroll
                for (int j = 0; j < 32; ++j) {
                    float xv = stile[t * 33 + j];
                    carry = (wbase + j == 0) ? xv : frelu(fmaf(carry, wgt, xv));
                    stile[t * 33 + j] = carry;
                }
            } else {
#pragma unroll
                for (int j = 31; j >= 0; --j) {
                    float xv = stile[t * 33 + j];
                    carry = (wbase + j == WD - 1) ? xv : frelu(fmaf(carry, wgt, xv));
                    stile[t * 33 + j] = carry;
                }
            }
            __syncthreads();
#pragma unroll
            for (int kk2 = 0; kk2 < 8; ++kk2) {
                int v = kk2 * 256 + t, row = v >> 3, cg = v & 7;
                *(ushort4*)(o + row * WD + wbase + cg * 4) =
                    pack4(stile[row * 33 + cg * 4 + 0], stile[row * 33 + cg * 4 + 1],
                          stile[row * 33 + cg * 4 + 2], stile[row * 33 + cg * 4 + 3]);
            }
        }
    }
}

// ---------------- MFMA conv: OUT[32][HW] = W[32][224] x CAT (linear) ----------------
// block 256 thr = 4 waves; wave owns 2 px-tiles (32 px); 7 K-slabs of 32.
// B-fragments gathered from linear CAT (8 x u16/slab-tile/lane, 4x32B segs/instr),
// ping-pong double buffer, fully static indexing.
// MODE 0: +bias -> F bf16 ; MODE 2: +bias, relu, dot(wo) -> fp32 out
template<int MODE>
__global__ __launch_bounds__(256) void conv_mfma(const u16* __restrict__ CAT,  // [kk][224][HW]
                                                 const u16* __restrict__ WP,   // [7][2][64][8]
                                                 const float* __restrict__ bias,
                                                 const float* __restrict__ wo,
                                                 u16* __restrict__ Fout,
                                                 float* __restrict__ out) {
    int t = threadIdx.x & 63;
    int w = threadIdx.x >> 6;
    int b = blockIdx.y;
    int tile0 = blockIdx.x * 8 + w * 2;
    // lane's B base: channel (t>>4)*8, col px = tile0*16 + (t&15)
    const u16* q0 = CAT + (size_t)b * 224 * HW + (size_t)((t >> 4) * 8) * HW
                  + (size_t)tile0 * 16 + (t & 15);
    const u16* q1 = q0 + 16;

    // A-fragment preload (14 x 16B, L2-hot)
    const short8* ap = (const short8*)WP;
    short8 A[7][2];
#pragma unroll
    for (int s = 0; s < 7; ++s) {
        A[s][0] = ap[(s * 2 + 0) * 64 + t];
        A[s][1] = ap[(s * 2 + 1) * 64 + t];
    }

    f32x4 acc[2][2];
#pragma unroll
    for (int tl = 0; tl < 2; ++tl)
#pragma unroll
        for (int m = 0; m < 2; ++m) acc[tl][m] = (f32x4){0.f, 0.f, 0.f, 0.f};

    u16 rb[2][2][8];   // [phase][tile][j] — compile-time indices after unroll
#pragma unroll
    for (int j = 0; j < 8; ++j) {
        rb[0][0][j] = q0[(size_t)j * HW];
        rb[0][1][j] = q1[(size_t)j * HW];
    }
#pragma unroll
    for (int s = 0; s < 7; ++s) {
        const int cur = s & 1, nxt = cur ^ 1;
        if (s < 6) {
#pragma unroll
            for (int j = 0; j < 8; ++j) {
                rb[nxt][0][j] = q0[(size_t)((s + 1) * 32 + j) * HW];
                rb[nxt][1][j] = q1[(size_t)((s + 1) * 32 + j) * HW];
            }
        }
        short8 B0, B1;
#pragma unroll
        for (int j = 0; j < 8; ++j) {
            B0[j] = (short)rb[cur][0][j];
            B1[j] = (short)rb[cur][1][j];
        }
        acc[0][0] = __builtin_amdgcn_mfma_f32_16x16x32_bf16(A[s][0], B0, acc[0][0], 0, 0, 0);
        acc[0][1] = __builtin_amdgcn_mfma_f32_16x16x32_bf16(A[s][1], B0, acc[0][1], 0, 0, 0);
        acc[1][0] = __builtin_amdgcn_mfma_f32_16x16x32_bf16(A[s][0], B1, acc[1][0], 0, 0, 0);
        acc[1][1] = __builtin_amdgcn_mfma_f32_16x16x32_bf16(A[s][1], B1, acc[1][1], 0, 0, 0);
    }

    // C/D: lane t holds col px=(t&15), rows ch=(t>>4)*4+r (+16*m)
    if (MODE == 0) {
        u16* fb = Fout + (size_t)b * 32 * HW;
#pragma unroll
        for (int tl = 0; tl < 2; ++tl) {
            int px = (tile0 + tl) * 16 + (t & 15);
#pragma unroll
            for (int m = 0; m < 2; ++m)
#pragma unroll
                for (int r = 0; r < 4; ++r) {
                    int ch = m * 16 + (t >> 4) * 4 + r;
                    fb[(size_t)ch * HW + px] = f2b(acc[tl][m][r] + bias[ch]);
                }
        }
    } else {
        float mres0 = 0.f, mres1 = 0.f;
#pragma unroll
        for (int m = 0; m < 2; ++m)
#pragma unroll
            for (int r = 0; r < 4; ++r) {
                int ch = m * 16 + (t >> 4) * 4 + r;
                float wv = wo[ch], bv = bias[ch];
                mres0 = fmaf(wv, frelu(acc[0][m][r] + bv), mres0);
                mres1 = fmaf(wv, frelu(acc[1][m][r] + bv), mres1);
            }
        mres0 += __shfl_xor(mres0, 16); mres0 += __shfl_xor(mres0, 32);
        mres1 += __shfl_xor(mres1, 16); mres1 += __shfl_xor(mres1, 32);
        if (t < 16) {
            out[(size_t)b * HW + (tile0 + 0) * 16 + t] = mres0;
            out[(size_t)b * HW + (tile0 + 1) * 16 + t] = mres1;
        }
    }
}

extern "C" void kernel_launch(void* const* d_in, const int* in_sizes, int n_in,
                              void* d_out, int out_size, void* d_ws, size_t ws_size,
                              hipStream_t stream) {
    const float* x    = (const float*)d_in[0];
    const float* w1   = (const float*)d_in[1];
    const float* b1   = (const float*)d_in[2];
    const float* w2   = (const float*)d_in[3];
    const float* b2   = (const float*)d_in[4];
    const float* w3   = (const float*)d_in[5];
    const float* b3   = (const float*)d_in[6];
    const float* wout = (const float*)d_in[7];
    const float* ir1  = (const float*)d_in[8];
    const float* ir2  = (const float*)d_in[9];

    const size_t fb   = (size_t)32 * HW * 2;        // F bf16: 4 MB/img
    const size_t cb   = (size_t)224 * HW * 2;       // CAT bf16: 29.36 MB/img
    const size_t wext = 64 * 32 * 4 + 2 * 7168 * 2;

    int K = 4;
    while (K > 1 && (size_t)K * (fb + cb) + wext > ws_size) K--;

    char* ws = (char*)d_ws;
    u16*   F    = (u16*)ws;   ws += (size_t)K * fb;
    u16*   CAT  = (u16*)ws;   ws += (size_t)K * cb;
    float* WT1  = (float*)ws; ws += 64 * 32 * 4;
    u16*   WP2  = (u16*)ws;   ws += 7168 * 2;
    u16*   WP3  = (u16*)ws;

    prep_weights<<<1, 256, 0, stream>>>(w1, w2, w3, WT1, WP2, WP3);

    for (int b0 = 0; b0 < 4; b0 += K) {
        int kk = (4 - b0 < K) ? (4 - b0) : K;
        conv1_k<<<dim3(HW / 256, kk), 256, 0, stream>>>(
            x + (size_t)b0 * 64 * HW, WT1, b1, F);
        scan_all<<<dim3(104, kk), 256, 0, stream>>>(F, CAT, ir1);
        conv_mfma<0><<<dim3(HW / 128, kk), 256, 0, stream>>>(
            CAT, WP2, b2, nullptr, F, nullptr);
        scan_all<<<dim3(104, kk), 256, 0, stream>>>(F, CAT, ir2);
        conv_mfma<2><<<dim3(HW / 128, kk), 256, 0, stream>>>(
            CAT, WP3, b3, wout, nullptr, (float*)d_out + (size_t)b0 * HW);
    }
}